// Round 3
// baseline (357.858 us; speedup 1.0000x reference)
//
#include <hip/hip_runtime.h>
#include <hip/hip_bf16.h>
#include <math.h>

#define BLOCK 256
#define WAVES_PER_BLOCK (BLOCK / 64)
#define GRID1 2048

typedef float f32x4 __attribute__((ext_vector_type(4)));

// Kernel 1: 8 lanes per row, 8 rows per wave, all 8 rows streamed
// simultaneously. All ~31 b128 loads per lane are independent (no cross-lane
// op until the whole 8-row tile is read), then ONE 3-level butterfly reduces
// all 8 rows in parallel. This removes the per-row 6-deep dependent shfl
// chain of the previous version (48 -> 5 dependent DS ops per 8 rows).
__global__ __launch_bounds__(BLOCK) void hinge_rows_kernel(
    const float* __restrict__ pred, const int* __restrict__ target,
    float* __restrict__ partial, int B, int C) {
  const int lane = threadIdx.x & 63;
  const int wave = threadIdx.x >> 6;
  const int g = lane & 7;   // position within the 8-lane row group
  const int r = lane >> 3;  // which of the wave's 8 rows
  const int gwave = blockIdx.x * WAVES_PER_BLOCK + wave;
  const int nwaves = gridDim.x * WAVES_PER_BLOCK;
  const int nvec = C >> 2;

  float sum = 0.0f;  // meaningful in lane 0

  for (int base = gwave * 8; base < B; base += nwaves * 8) {
    // Prologue: lane l<8 loads target + correct score for row base+l
    // (8 scattered addresses in flight in one instruction each).
    int ty = 0;
    float corr = 0.0f;
    const bool own = (lane < 8) && (base + lane < B);
    if (own) {
      ty = target[base + lane];
      corr = pred[(size_t)(base + lane) * (size_t)C + ty];
    }

    const int row = base + r;
    const int rowv = (row < B) ? row : (B - 1);  // clamp; result masked later
    const int y = __shfl(ty, r);                 // this group's target class
    const float* rp = pred + (size_t)rowv * (size_t)C;
    const f32x4* rp4 = (const f32x4*)rp;

    float m = -INFINITY;
    #pragma unroll 4
    for (int i = g; i < nvec; i += 8) {
      f32x4 v = rp4[i];
      const int b0 = i << 2;
      v.x = (b0 + 0 == y) ? -INFINITY : v.x;
      v.y = (b0 + 1 == y) ? -INFINITY : v.y;
      v.z = (b0 + 2 == y) ? -INFINITY : v.z;
      v.w = (b0 + 3 == y) ? -INFINITY : v.w;
      m = fmaxf(m, fmaxf(fmaxf(v.x, v.y), fmaxf(v.z, v.w)));
    }
    // scalar tail if C % 4 != 0 (C=1000 -> no-op)
    for (int c = (nvec << 2) + g; c < C; c += 8) {
      if (c != y) m = fmaxf(m, rp[c]);
    }

    // One 3-level butterfly: xor masks 1,2,4 stay inside each 8-lane group,
    // so all 8 rows reduce in parallel.
    m = fmaxf(m, __shfl_xor(m, 1));
    m = fmaxf(m, __shfl_xor(m, 2));
    m = fmaxf(m, __shfl_xor(m, 4));

    // Lanes 0..7 pick up the max of row base+lane (it lives in lanes lane*8..).
    const float M = __shfl(m, (lane & 7) * 8);
    float h = fmaxf(M - corr + 1.0f, 0.0f);
    h = own ? h : 0.0f;
    // Sum the 8 per-row hinges into lane 0 (masks 1,2,4 stay within 0..7).
    h += __shfl_xor(h, 1);
    h += __shfl_xor(h, 2);
    h += __shfl_xor(h, 4);
    sum += h;
  }

  __shared__ float lsum[WAVES_PER_BLOCK];
  if (lane == 0) lsum[wave] = sum;
  __syncthreads();
  if (threadIdx.x == 0) {
    float s = 0.0f;
    #pragma unroll
    for (int w = 0; w < WAVES_PER_BLOCK; ++w) s += lsum[w];
    partial[blockIdx.x] = s;
  }
}

// Kernel 2: reduce GRID1 partials, scale by 1/B, write scalar output.
__global__ __launch_bounds__(BLOCK) void hinge_reduce_kernel(
    const float* __restrict__ partial, int n, float* __restrict__ out,
    float scale) {
  float s = 0.0f;
  for (int i = threadIdx.x; i < n; i += BLOCK) s += partial[i];

  #pragma unroll
  for (int off = 32; off; off >>= 1) s += __shfl_xor(s, off);

  const int lane = threadIdx.x & 63;
  const int wave = threadIdx.x >> 6;
  __shared__ float lsum[WAVES_PER_BLOCK];
  if (lane == 0) lsum[wave] = s;
  __syncthreads();
  if (threadIdx.x == 0) {
    float t = 0.0f;
    #pragma unroll
    for (int w = 0; w < WAVES_PER_BLOCK; ++w) t += lsum[w];
    out[0] = t * scale;
  }
}

extern "C" void kernel_launch(void* const* d_in, const int* in_sizes, int n_in,
                              void* d_out, int out_size, void* d_ws, size_t ws_size,
                              hipStream_t stream) {
  const float* pred = (const float*)d_in[0];
  const int* target = (const int*)d_in[1];
  float* out = (float*)d_out;
  float* partial = (float*)d_ws;

  const int B = in_sizes[1];
  const int C = in_sizes[0] / B;

  hinge_rows_kernel<<<GRID1, BLOCK, 0, stream>>>(pred, target, partial, B, C);
  hinge_reduce_kernel<<<1, BLOCK, 0, stream>>>(partial, GRID1, out, 1.0f / (float)B);
}